// Round 13
// baseline (42.486 us; speedup 1.0000x reference)
//
#include <hip/hip_runtime.h>
#include <hip/hip_bf16.h>

#define S_ 1024
#define E_ 768
#define H_ 12

typedef __bf16  bf16x8 __attribute__((ext_vector_type(8)));
typedef float   f32x4  __attribute__((ext_vector_type(4)));
typedef unsigned short u16x4 __attribute__((ext_vector_type(4)));

__device__ __forceinline__ unsigned short f2bf(float f) {
    union { float f; unsigned u; } a; a.f = f;
    unsigned u = a.u;
    u += 0x7FFFu + ((u >> 16) & 1u);   // RNE
    return (unsigned short)(u >> 16);
}

// LDS tile layout: R rows x 64 bf16 (128B/row, 8x16B chunks).
// Physical chunk (row, cb) holds global chunk (row, cb ^ (row&7)).
__device__ __forceinline__ bf16x8 ld_frag(const char* lbase, int row, int kk, int lane) {
    int cbyte = (kk * 64 + ((lane >> 4) * 16)) ^ ((row & 7) << 4);
    return *(const bf16x8*)(lbase + row * 128 + cbyte);
}

// -------- prep: Wq*(lin_w/sqrt8)->bf16, Wk->bf16, bq scaled, q/k->bf16. One 1D launch. --------
__global__ __launch_bounds__(256) void prep_cast_kernel(
    const float* __restrict__ q_in, const float* __restrict__ k_in,
    const float* __restrict__ Wq, const float* __restrict__ Wk,
    const float* __restrict__ bq, const float* __restrict__ lin_w,
    unsigned short* __restrict__ Wqbf, unsigned short* __restrict__ Wkbf,
    unsigned short* __restrict__ qbf, unsigned short* __restrict__ kbf,
    float* __restrict__ bqs)
{
    const float invs = 0.35355339059327373f; // 1/sqrt(8)
    int u = blockIdx.x * 256 + threadIdx.x;  // float4 index
    if (u < 147456) {                        // Wq (scaled)
        int i = u * 4;
        int n = i / E_;
        float w = lin_w[(n & 63) >> 3] * invs;
        float4 v = *(const float4*)(Wq + i);
        *(ushort4*)(Wqbf + i) = make_ushort4(f2bf(v.x * w), f2bf(v.y * w), f2bf(v.z * w), f2bf(v.w * w));
        if (u < E_) bqs[u] = bq[u] * (lin_w[(u & 63) >> 3] * invs);
    } else if (u < 294912) {                 // Wk
        int i = (u - 147456) * 4;
        float4 v = *(const float4*)(Wk + i);
        *(ushort4*)(Wkbf + i) = make_ushort4(f2bf(v.x), f2bf(v.y), f2bf(v.z), f2bf(v.w));
    } else if (u < 688128) {                 // q
        int i = (u - 294912) * 4;
        float4 v = *(const float4*)(q_in + i);
        *(ushort4*)(qbf + i) = make_ushort4(f2bf(v.x), f2bf(v.y), f2bf(v.z), f2bf(v.w));
    } else {                                 // k
        int i = (u - 688128) * 4;
        float4 v = *(const float4*)(k_in + i);
        *(ushort4*)(kbf + i) = make_ushort4(f2bf(v.x), f2bf(v.y), f2bf(v.z), f2bf(v.w));
    }
}

// ---------------- proj: P[m,n] = sum_k X[m,k]*Wbf[n,k] + bias[n], bf16 out ----------------
// (unchanged from R12: ring-3 counted-vmcnt pipeline + setprio, all-bf16 global_load_lds)
__global__ __launch_bounds__(256) void proj_kernel(
    const unsigned short* __restrict__ qbf, const unsigned short* __restrict__ kbf,
    const unsigned short* __restrict__ Wqbf, const unsigned short* __restrict__ Wkbf,
    const float* __restrict__ bqs, const float* __restrict__ bk,
    unsigned short* __restrict__ qs, unsigned short* __restrict__ kp)
{
    __shared__ char lds[3 * 16384];   // ring of 3 bufs: each {X 8K | W 8K}

    int lid = blockIdx.x;
    int swz = (lid & 7) * 96 + (lid >> 3);   // XCD-chunked (768 % 8 == 0, bijective)
    int z  = swz / 384;
    int rem = swz - z * 384;
    int ty = rem / 12, tx = rem - ty * 12;
    int tm = ty * 64, tn = tx * 64;

    const unsigned short* X = z ? kbf : qbf;
    const unsigned short* W = z ? Wkbf : Wqbf;
    const float* bias       = z ? bk   : bqs;
    unsigned short* P       = z ? kp   : qs;

    int tid = threadIdx.x, lane = tid & 63, wid = tid >> 6;
    int wn = wid >> 1, wm = wid & 1;

    int c0 = tid,        r0 = c0 >> 3, g0 = ((c0 & 7) ^ (r0 & 7)) * 8;
    int c1 = 256 + tid,  r1 = c1 >> 3, g1 = ((c1 & 7) ^ (r1 & 7)) * 8;

    const unsigned short* Xg = X + (size_t)tm * E_;
    const unsigned short* Wg = W + (size_t)tn * E_;

#define GLL(src, dst) __builtin_amdgcn_global_load_lds( \
        (const __attribute__((address_space(1))) void*)(src), \
        (__attribute__((address_space(3))) void*)(dst), 16, 0, 0)
#define STAGE(kb, buf) { \
    char* xb = lds + (buf) * 16384; \
    char* wb = xb + 8192; \
    GLL(Xg + (size_t)r0 * E_ + (kb) + g0, xb + c0 * 16); \
    GLL(Xg + (size_t)r1 * E_ + (kb) + g1, xb + c1 * 16); \
    GLL(Wg + (size_t)r0 * E_ + (kb) + g0, wb + c0 * 16); \
    GLL(Wg + (size_t)r1 * E_ + (kb) + g1, wb + c1 * 16); }

    f32x4 acc[2][2];
#pragma unroll
    for (int nj = 0; nj < 2; ++nj) {
        int n0 = tn + wn * 32 + nj * 16 + ((lane >> 4) << 2);
        float4 b4 = *(const float4*)(bias + n0);
#pragma unroll
        for (int mi = 0; mi < 2; ++mi)
            acc[nj][mi] = f32x4{b4.x, b4.y, b4.z, b4.w};
    }

#define COMPSTEP(buf) { \
    const char* Xc = lds + (buf) * 16384; \
    const char* Wc = Xc + 8192; \
    __builtin_amdgcn_s_setprio(1); \
    _Pragma("unroll") \
    for (int kk = 0; kk < 2; ++kk) { \
        bf16x8 a0 = ld_frag(Wc, wn * 32 + (lane & 15), kk, lane); \
        bf16x8 a1 = ld_frag(Wc, wn * 32 + 16 + (lane & 15), kk, lane); \
        bf16x8 b0 = ld_frag(Xc, wm * 32 + (lane & 15), kk, lane); \
        bf16x8 b1 = ld_frag(Xc, wm * 32 + 16 + (lane & 15), kk, lane); \
        acc[0][0] = __builtin_amdgcn_mfma_f32_16x16x32_bf16(a0, b0, acc[0][0], 0, 0, 0); \
        acc[0][1] = __builtin_amdgcn_mfma_f32_16x16x32_bf16(a0, b1, acc[0][1], 0, 0, 0); \
        acc[1][0] = __builtin_amdgcn_mfma_f32_16x16x32_bf16(a1, b0, acc[1][0], 0, 0, 0); \
        acc[1][1] = __builtin_amdgcn_mfma_f32_16x16x32_bf16(a1, b1, acc[1][1], 0, 0, 0); \
    } \
    __builtin_amdgcn_s_setprio(0); }

    // prologue: tiles 0,1 in flight
    STAGE(0, 0);
    STAGE(64, 1);

    int cur = 0, nxt = 2;
    for (int t = 0; t < 10; ++t) {
        asm volatile("s_waitcnt vmcnt(4)" ::: "memory");   // my tile-t loads done (4 newer)
        __builtin_amdgcn_s_barrier();                      // raw: no implicit drain
        __builtin_amdgcn_sched_barrier(0);
        STAGE((t + 2) * 64, nxt);                          // stage t+2 (after barrier: safe reuse)
        COMPSTEP(cur);
        cur = cur == 2 ? 0 : cur + 1;
        nxt = nxt == 2 ? 0 : nxt + 1;
    }
    // tail: t=10 (tile 11 still in flight), t=11
    asm volatile("s_waitcnt vmcnt(4)" ::: "memory");
    __builtin_amdgcn_s_barrier();
    __builtin_amdgcn_sched_barrier(0);
    COMPSTEP(cur);
    cur = cur == 2 ? 0 : cur + 1;
    asm volatile("s_waitcnt vmcnt(0)" ::: "memory");
    __builtin_amdgcn_s_barrier();
    __builtin_amdgcn_sched_barrier(0);
    COMPSTEP(cur);

#pragma unroll
    for (int nj = 0; nj < 2; ++nj)
#pragma unroll
        for (int mi = 0; mi < 2; ++mi) {
            int n0 = tn + wn * 32 + nj * 16 + ((lane >> 4) << 2);
            int m  = tm + wm * 32 + mi * 16 + (lane & 15);
            u16x4 pk;
            pk[0] = f2bf(acc[nj][mi][0]); pk[1] = f2bf(acc[nj][mi][1]);
            pk[2] = f2bf(acc[nj][mi][2]); pk[3] = f2bf(acc[nj][mi][3]);
            *(u16x4*)(P + (size_t)m * E_ + n0) = pk;
        }
#undef GLL
#undef STAGE
#undef COMPSTEP
}

// ---------------- scores: per (b,h): out[i,j] = qs_i . kp_j + lin_b, fp32 out ----------------
// R13 deltas: (a) BOTH K stages + qf issued before ONE __syncthreads (no second barrier —
// no drain ever waits on stores); (b) store loops ni-outer/mj-inner so the two 64B halves
// of each 128B L2 line are written by ADJACENT instructions (write-merge locality).
__global__ __launch_bounds__(256) void scores_kernel(
    const unsigned short* __restrict__ qs, const unsigned short* __restrict__ kp,
    const float* __restrict__ lin_b, float* __restrict__ out)
{
    __shared__ char lds[32768];   // Kb0, Kb1: 16KB each (128 rows x 64 bf16)

    int lid = blockIdx.x;
    int swz = (lid & 7) * 96 + (lid >> 3);   // 768 % 8 == 0, bijective
    int z   = swz >> 5;                      // 32 blocks per head
    int rem = swz & 31;
    int iy  = rem >> 2, jx = rem & 3;
    int b = z / H_, h = z - b * H_;

    int tid = threadIdx.x, lane = tid & 63, wid = tid >> 6;
    int wj = wid >> 1, wi = wid & 1;
    int ti = iy * 128, tj = jx * 256;

    const unsigned short* Qg = qs + (size_t)(b * S_) * E_ + h * 64;
    const unsigned short* Kg = kp + (size_t)(b * S_) * E_ + h * 64;

#define STAGEK(jbase, buf) { \
    char* lb = lds + (buf) * 16384; \
    _Pragma("unroll") \
    for (int pass = 0; pass < 4; ++pass) { \
        int c = pass * 256 + tid; \
        int row = c >> 3, cbg = (c & 7) ^ (row & 7); \
        __builtin_amdgcn_global_load_lds( \
            (const __attribute__((address_space(1))) void*)(Kg + (size_t)((jbase) + row) * E_ + cbg * 8), \
            (__attribute__((address_space(3))) void*)(lb + c * 16), 16, 0, 0); \
    } }

    // issue EVERYTHING up front: qf (8 loads) + Kb0 (4 glls) + Kb1 (4 glls)
    bf16x8 qf[2][4];
    int qrow = ti + wi * 64 + (lane & 15);
#pragma unroll
    for (int ni = 0; ni < 4; ++ni)
#pragma unroll
        for (int kk = 0; kk < 2; ++kk)
            qf[kk][ni] = *(const bf16x8*)(Qg + (size_t)(qrow + ni * 16) * E_ + kk * 32 + ((lane >> 4) * 8));
    STAGEK(tj, 0);
    STAGEK(tj + 128, 1);

    float lb0 = lin_b[0];
    float* O = out + ((size_t)z << 20);

    __syncthreads();                       // single full drain: qf + Kb0 + Kb1 all ready

    f32x4 acc[4][4];

    // ---- sub 0: compute ----
#pragma unroll
    for (int mj = 0; mj < 4; ++mj)
#pragma unroll
        for (int ni = 0; ni < 4; ++ni) acc[mj][ni] = f32x4{lb0, lb0, lb0, lb0};
#pragma unroll
    for (int kk = 0; kk < 2; ++kk) {
        bf16x8 a[4];
#pragma unroll
        for (int mj = 0; mj < 4; ++mj) a[mj] = ld_frag(lds, wj * 64 + mj * 16 + (lane & 15), kk, lane);
#pragma unroll
        for (int mj = 0; mj < 4; ++mj)
#pragma unroll
            for (int ni = 0; ni < 4; ++ni)
                acc[mj][ni] = __builtin_amdgcn_mfma_f32_16x16x32_bf16(a[mj], qf[kk][ni], acc[mj][ni], 0, 0, 0);
    }

    // ---- sub 0: store (ni outer, mj inner: 128B-line halves adjacent) ----
#pragma unroll
    for (int ni = 0; ni < 4; ++ni)
#pragma unroll
        for (int mj = 0; mj < 4; ++mj) {
            int i  = ti + wi * 64 + ni * 16 + (lane & 15);
            int j0 = tj + wj * 64 + mj * 16 + ((lane >> 4) << 2);
            *(f32x4*)(O + (size_t)i * S_ + j0) = acc[mj][ni];
        }

    // ---- sub 1: compute (Kb1 already drained at the single barrier) ----
#pragma unroll
    for (int mj = 0; mj < 4; ++mj)
#pragma unroll
        for (int ni = 0; ni < 4; ++ni) acc[mj][ni] = f32x4{lb0, lb0, lb0, lb0};
#pragma unroll
    for (int kk = 0; kk < 2; ++kk) {
        bf16x8 a[4];
#pragma unroll
        for (int mj = 0; mj < 4; ++mj) a[mj] = ld_frag(lds + 16384, wj * 64 + mj * 16 + (lane & 15), kk, lane);
#pragma unroll
        for (int mj = 0; mj < 4; ++mj)
#pragma unroll
            for (int ni = 0; ni < 4; ++ni)
                acc[mj][ni] = __builtin_amdgcn_mfma_f32_16x16x32_bf16(a[mj], qf[kk][ni], acc[mj][ni], 0, 0, 0);
    }

    // ---- sub 1: store ----
#pragma unroll
    for (int ni = 0; ni < 4; ++ni)
#pragma unroll
        for (int mj = 0; mj < 4; ++mj) {
            int i  = ti + wi * 64 + ni * 16 + (lane & 15);
            int j0 = tj + 128 + wj * 64 + mj * 16 + ((lane >> 4) << 2);
            *(f32x4*)(O + (size_t)i * S_ + j0) = acc[mj][ni];
        }
#undef STAGEK
}

extern "C" void kernel_launch(void* const* d_in, const int* in_sizes, int n_in,
                              void* d_out, int out_size, void* d_ws, size_t ws_size,
                              hipStream_t stream)
{
    const float* k_in  = (const float*)d_in[0];
    const float* q_in  = (const float*)d_in[1];
    const float* Wq_w  = (const float*)d_in[2];
    const float* Wq_b  = (const float*)d_in[3];
    const float* Wk_w  = (const float*)d_in[4];
    const float* Wk_b  = (const float*)d_in[5];
    const float* lin_w = (const float*)d_in[6];
    const float* lin_b = (const float*)d_in[7];
    float* out = (float*)d_out;

    char* ws = (char*)d_ws;
    unsigned short* Wqbf = (unsigned short*)(ws + 0);
    unsigned short* Wkbf = (unsigned short*)(ws + 1179648);
    float*          bqs  = (float*)        (ws + 2359296);
    unsigned short* qbf  = (unsigned short*)(ws + 2362368);
    unsigned short* kbf  = (unsigned short*)(ws + 5508096);
    unsigned short* qsb  = (unsigned short*)(ws + 8653824);
    unsigned short* kpb  = (unsigned short*)(ws + 11799552);

    // 1) prep+cast: Wq scaled->bf16, Wk->bf16, bqs, q->bf16, k->bf16
    prep_cast_kernel<<<dim3(4224), dim3(256), 0, stream>>>(q_in, k_in, Wq_w, Wk_w, Wq_b, lin_w,
                                                           Wqbf, Wkbf, qbf, kbf, bqs);
    // 2) projections: counted-vmcnt ring-3 pipeline + setprio
    proj_kernel<<<dim3(768), dim3(256), 0, stream>>>(qbf, kbf, Wqbf, Wkbf, bqs, Wk_b, qsb, kpb);
    // 3) scores: single-barrier, line-paired stores
    scores_kernel<<<dim3(768), dim3(256), 0, stream>>>(qsb, kpb, lin_b, out);
}